// Round 1
// baseline (261.580 us; speedup 1.0000x reference)
//
#include <hip/hip_runtime.h>
#include <math.h>

#define LAM 0.9f
#define EPS 1e-8f

// Per-row weight: top-2 of 10 probs -> exp(0.9*log(fir+eps) + 0.1*log(fir-sec+eps))
__device__ __forceinline__ float row_weight(const float* __restrict__ p) {
    float fir = -3.4e38f, sec = -3.4e38f;
#pragma unroll
    for (int i = 0; i < 10; ++i) {
        float x = p[i];
        if (x > fir) { sec = fir; fir = x; }
        else if (x > sec) { sec = x; }
    }
    return expf(LAM * logf(fir + EPS) + (1.0f - LAM) * logf(fir - sec + EPS));
}

__global__ __launch_bounds__(256) void fused_blend_kernel(
    const float* __restrict__ v1, const float* __restrict__ p1,
    const float* __restrict__ v2, const float* __restrict__ p2,
    float* __restrict__ out, int N)
{
    const int group = threadIdx.x >> 5;   // 0..7: which row this 32-lane group owns
    const int lane  = threadIdx.x & 31;   // 0..31: which float4 of the 128-wide row
    const long long row = (long long)blockIdx.x * 8 + group;
    if (row >= N) return;

    float beta1 = 0.0f, beta2 = 0.0f;
    if (lane == 0) {
        const float w1 = row_weight(p1 + row * 10);
        const float w2 = row_weight(p2 + row * 10);
        const float denom = w1 + w2;
        beta1 = w1 / denom;
        beta2 = w2 / denom;
    }
    beta1 = __shfl(beta1, 0, 32);
    beta2 = __shfl(beta2, 0, 32);

    const float4 va = *((const float4*)(v1 + row * 128) + lane);
    const float4 vb = *((const float4*)(v2 + row * 128) + lane);
    float4 r;
    r.x = beta1 * va.x + beta2 * vb.x;
    r.y = beta1 * va.y + beta2 * vb.y;
    r.z = beta1 * va.z + beta2 * vb.z;
    r.w = beta1 * va.w + beta2 * vb.w;
    *((float4*)(out + row * 128) + lane) = r;
}

extern "C" void kernel_launch(void* const* d_in, const int* in_sizes, int n_in,
                              void* d_out, int out_size, void* d_ws, size_t ws_size,
                              hipStream_t stream) {
    const float* v1 = (const float*)d_in[0];
    const float* p1 = (const float*)d_in[1];
    const float* v2 = (const float*)d_in[2];
    const float* p2 = (const float*)d_in[3];
    float* out = (float*)d_out;
    const int N = in_sizes[1] / 10;  // prob_v1 is (N, 10)

    const int rows_per_block = 8;    // 256 threads / 32 lanes-per-row
    const int blocks = (N + rows_per_block - 1) / rows_per_block;
    fused_blend_kernel<<<blocks, 256, 0, stream>>>(v1, p1, v2, p2, out, N);
}

// Round 2
// 164.994 us; speedup vs baseline: 1.5854x; 1.5854x over previous
//
#include <hip/hip_runtime.h>
#include <math.h>

#define LAM 0.9f
#define EPS 1e-8f
#define ROWS_PER_BLOCK 256

// log-weight: 0.9*log(fir+eps) + 0.1*log(fir-sec+eps) over 10 probs
__device__ __forceinline__ float row_logw(const float* __restrict__ p) {
    float fir = -3.4e38f, sec = -3.4e38f;
    // 5 x float2 loads (rows are 40B, always 8B-aligned)
    const float2* p2 = (const float2*)p;
#pragma unroll
    for (int i = 0; i < 5; ++i) {
        float2 x = p2[i];
        if (x.x > fir) { sec = fir; fir = x.x; }
        else if (x.x > sec) { sec = x.x; }
        if (x.y > fir) { sec = fir; fir = x.y; }
        else if (x.y > sec) { sec = x.y; }
    }
    return LAM * __logf(fir + EPS) + (1.0f - LAM) * __logf(fir - sec + EPS);
}

__global__ __launch_bounds__(256) void fused_blend_kernel(
    const float* __restrict__ v1, const float* __restrict__ p1,
    const float* __restrict__ v2, const float* __restrict__ p2,
    float* __restrict__ out, int N)
{
    __shared__ float b1s[ROWS_PER_BLOCK];

    const int t = threadIdx.x;
    const long long rowBase = (long long)blockIdx.x * ROWS_PER_BLOCK;
    const long long row = rowBase + t;

    // Phase 1: every thread computes beta1 for its own row (full parallelism).
    if (row < N) {
        const float a1 = row_logw(p1 + row * 10);
        const float a2 = row_logw(p2 + row * 10);
        // beta1 = w1/(w1+w2) = sigmoid(a1-a2)
        b1s[t] = 1.0f / (1.0f + __expf(a2 - a1));
    }
    __syncthreads();

    // Phase 2: stream the 256-row x 128-col tile as coalesced float4.
    const long long gEnd  = (long long)N * 32;          // total float4 count
    const long long gBase = rowBase * 32;
#pragma unroll 8
    for (int k = 0; k < 32; ++k) {
        const long long g = gBase + (long long)k * 256 + t;
        if (g < gEnd) {
            const int localRow = (int)((long long)k * 256 + t) >> 5;
            const float beta1 = b1s[localRow];
            const float beta2 = 1.0f - beta1;
            const float4 va = ((const float4*)v1)[g];
            const float4 vb = ((const float4*)v2)[g];
            float4 r;
            r.x = beta1 * va.x + beta2 * vb.x;
            r.y = beta1 * va.y + beta2 * vb.y;
            r.z = beta1 * va.z + beta2 * vb.z;
            r.w = beta1 * va.w + beta2 * vb.w;
            ((float4*)out)[g] = r;
        }
    }
}

extern "C" void kernel_launch(void* const* d_in, const int* in_sizes, int n_in,
                              void* d_out, int out_size, void* d_ws, size_t ws_size,
                              hipStream_t stream) {
    const float* v1 = (const float*)d_in[0];
    const float* p1 = (const float*)d_in[1];
    const float* v2 = (const float*)d_in[2];
    const float* p2 = (const float*)d_in[3];
    float* out = (float*)d_out;
    const int N = in_sizes[1] / 10;  // prob_v1 is (N, 10)

    const int blocks = (N + ROWS_PER_BLOCK - 1) / ROWS_PER_BLOCK;
    fused_blend_kernel<<<blocks, 256, 0, stream>>>(v1, p1, v2, p2, out, N);
}

// Round 4
// 164.566 us; speedup vs baseline: 1.5895x; 1.0026x over previous
//
#include <hip/hip_runtime.h>
#include <math.h>

#define LAM 0.9f
#define EPS 1e-8f
#define ROWS_PER_BLOCK 256

typedef float  f32x4 __attribute__((ext_vector_type(4)));  // native vector: OK for nontemporal builtins
typedef float  f32x2 __attribute__((ext_vector_type(2)));

// log-weight: 0.9*log(fir+eps) + 0.1*log(fir-sec+eps) over 10 probs
__device__ __forceinline__ float row_logw(const float* __restrict__ p) {
    float fir = -3.4e38f, sec = -3.4e38f;
    const f32x2* p2 = (const f32x2*)p;   // rows are 40B -> 8B-aligned
#pragma unroll
    for (int i = 0; i < 5; ++i) {
        f32x2 x = p2[i];
        if (x.x > fir) { sec = fir; fir = x.x; }
        else if (x.x > sec) { sec = x.x; }
        if (x.y > fir) { sec = fir; fir = x.y; }
        else if (x.y > sec) { sec = x.y; }
    }
    return LAM * __logf(fir + EPS) + (1.0f - LAM) * __logf(fir - sec + EPS);
}

__global__ __launch_bounds__(256) void fused_blend_kernel(
    const float* __restrict__ v1, const float* __restrict__ p1,
    const float* __restrict__ v2, const float* __restrict__ p2,
    float* __restrict__ out, int N)
{
    __shared__ float b1s[ROWS_PER_BLOCK];

    const int t = threadIdx.x;
    const int rowBase = blockIdx.x * ROWS_PER_BLOCK;   // N=500k -> fits int
    const int row = rowBase + t;

    // Phase 1: every thread computes beta1 for its own row.
    if (row < N) {
        const float a1 = row_logw(p1 + (size_t)row * 10);
        const float a2 = row_logw(p2 + (size_t)row * 10);
        b1s[t] = 1.0f / (1.0f + __expf(a2 - a1));   // w1/(w1+w2) = sigmoid(a1-a2)
    }
    __syncthreads();

    // Phase 2: stream the 256-row x 128-col tile as coalesced float4.
    // Flat float4 index: max N*32 = 16M, fits in 32-bit.
    const unsigned gEnd  = (unsigned)N * 32u;
    const unsigned gBase = (unsigned)rowBase * 32u;
    const f32x4* __restrict__ v1q = (const f32x4*)v1;
    const f32x4* __restrict__ v2q = (const f32x4*)v2;
    f32x4* __restrict__ outq = (f32x4*)out;
#pragma unroll 8
    for (int k = 0; k < 32; ++k) {
        const unsigned g = gBase + (unsigned)k * 256u + (unsigned)t;
        if (g < gEnd) {
            const int localRow = (k * 256 + t) >> 5;
            const float beta1 = b1s[localRow];
            const float beta2 = 1.0f - beta1;
            const f32x4 va = v1q[g];
            const f32x4 vb = v2q[g];
            f32x4 r = beta1 * va + beta2 * vb;
            // Output is write-once, never read: stream past L2/L3 so inputs
            // keep the cache capacity.
            __builtin_nontemporal_store(r, outq + g);
        }
    }
}

extern "C" void kernel_launch(void* const* d_in, const int* in_sizes, int n_in,
                              void* d_out, int out_size, void* d_ws, size_t ws_size,
                              hipStream_t stream) {
    const float* v1 = (const float*)d_in[0];
    const float* p1 = (const float*)d_in[1];
    const float* v2 = (const float*)d_in[2];
    const float* p2 = (const float*)d_in[3];
    float* out = (float*)d_out;
    const int N = in_sizes[1] / 10;  // prob_v1 is (N, 10)

    const int blocks = (N + ROWS_PER_BLOCK - 1) / ROWS_PER_BLOCK;
    fused_blend_kernel<<<blocks, 256, 0, stream>>>(v1, p1, v2, p2, out, N);
}

// Round 5
// 153.049 us; speedup vs baseline: 1.7091x; 1.0753x over previous
//
#include <hip/hip_runtime.h>
#include <math.h>

#define LAM 0.9f
#define EPS 1e-8f
#define RPB 256   // rows per block

typedef float f32x4 __attribute__((ext_vector_type(4)));
typedef float f32x2 __attribute__((ext_vector_type(2)));

// log-weight: 0.9*log(fir+eps) + 0.1*log(fir-sec+eps) over 10 probs
__device__ __forceinline__ float row_logw(const float* __restrict__ p) {
    float fir = -3.4e38f, sec = -3.4e38f;
    const f32x2* p2 = (const f32x2*)p;   // rows are 40B -> 8B-aligned
#pragma unroll
    for (int i = 0; i < 5; ++i) {
        f32x2 x = p2[i];
        if (x.x > fir) { sec = fir; fir = x.x; }
        else if (x.x > sec) { sec = x.x; }
        if (x.y > fir) { sec = fir; fir = x.y; }
        else if (x.y > sec) { sec = x.y; }
    }
    return LAM * __logf(fir + EPS) + (1.0f - LAM) * __logf(fir - sec + EPS);
}

__global__ __launch_bounds__(256) void fused_blend_kernel(
    const float* __restrict__ v1, const float* __restrict__ p1,
    const float* __restrict__ v2, const float* __restrict__ p2,
    float* __restrict__ out, int N)
{
    __shared__ float b1s[RPB];
    const int t   = threadIdx.x;
    const int t32 = t >> 5;
    const int rowBase = blockIdx.x * RPB;
    const int row = rowBase + t;
    const unsigned gBase = (unsigned)rowBase * 32u + (unsigned)t;   // flat float4 index

    const f32x4* __restrict__ v1q = (const f32x4*)v1;
    const f32x4* __restrict__ v2q = (const f32x4*)v2;
    f32x4* __restrict__ outq = (f32x4*)out;

    const bool full = (rowBase + RPB <= N);   // uniform per block

    if (full) {
        f32x4 aA[8], bA[8], aB[8], bB[8];

        // Prefetch batch A (k=0..7) BEFORE the beta phase: HBM latency hides
        // under the prob loads + transcendentals (issue-early pattern).
#pragma unroll
        for (int j = 0; j < 8; ++j) {
            aA[j] = v1q[gBase + (unsigned)j * 256u];
            bA[j] = v2q[gBase + (unsigned)j * 256u];
        }

        // Phase 1: every thread computes beta1 for its own row.
        const float a1 = row_logw(p1 + (size_t)row * 10);
        const float a2 = row_logw(p2 + (size_t)row * 10);
        b1s[t] = 1.0f / (1.0f + __expf(a2 - a1));   // w1/(w1+w2) = sigmoid(a1-a2)
        __syncthreads();

        // Phase 2: 2-stage pipeline, 8-deep batches (load next || blend+store cur).
        // load B(8..15), store A(0..7)
#pragma unroll
        for (int j = 0; j < 8; ++j) {
            aB[j] = v1q[gBase + (unsigned)(8 + j) * 256u];
            bB[j] = v2q[gBase + (unsigned)(8 + j) * 256u];
        }
#pragma unroll
        for (int j = 0; j < 8; ++j) {
            const float be1 = b1s[j * 8 + t32];
            __builtin_nontemporal_store(be1 * aA[j] + (1.0f - be1) * bA[j],
                                        outq + gBase + (unsigned)j * 256u);
        }
        // load A(16..23), store B(8..15)
#pragma unroll
        for (int j = 0; j < 8; ++j) {
            aA[j] = v1q[gBase + (unsigned)(16 + j) * 256u];
            bA[j] = v2q[gBase + (unsigned)(16 + j) * 256u];
        }
#pragma unroll
        for (int j = 0; j < 8; ++j) {
            const float be1 = b1s[(8 + j) * 8 + t32];
            __builtin_nontemporal_store(be1 * aB[j] + (1.0f - be1) * bB[j],
                                        outq + gBase + (unsigned)(8 + j) * 256u);
        }
        // load B(24..31), store A(16..23)
#pragma unroll
        for (int j = 0; j < 8; ++j) {
            aB[j] = v1q[gBase + (unsigned)(24 + j) * 256u];
            bB[j] = v2q[gBase + (unsigned)(24 + j) * 256u];
        }
#pragma unroll
        for (int j = 0; j < 8; ++j) {
            const float be1 = b1s[(16 + j) * 8 + t32];
            __builtin_nontemporal_store(be1 * aA[j] + (1.0f - be1) * bA[j],
                                        outq + gBase + (unsigned)(16 + j) * 256u);
        }
        // store B(24..31)
#pragma unroll
        for (int j = 0; j < 8; ++j) {
            const float be1 = b1s[(24 + j) * 8 + t32];
            __builtin_nontemporal_store(be1 * aB[j] + (1.0f - be1) * bB[j],
                                        outq + gBase + (unsigned)(24 + j) * 256u);
        }
    } else {
        // Tail block (at most one): fully bounds-checked path.
        if (row < N) {
            const float a1 = row_logw(p1 + (size_t)row * 10);
            const float a2 = row_logw(p2 + (size_t)row * 10);
            b1s[t] = 1.0f / (1.0f + __expf(a2 - a1));
        }
        __syncthreads();
        const unsigned gEnd = (unsigned)N * 32u;
        for (int k = 0; k < 32; ++k) {
            const unsigned g = (unsigned)rowBase * 32u + (unsigned)k * 256u + (unsigned)t;
            if (g < gEnd) {
                const float be1 = b1s[(k * 256 + t) >> 5];
                const f32x4 va = v1q[g];
                const f32x4 vb = v2q[g];
                __builtin_nontemporal_store(be1 * va + (1.0f - be1) * vb, outq + g);
            }
        }
    }
}

extern "C" void kernel_launch(void* const* d_in, const int* in_sizes, int n_in,
                              void* d_out, int out_size, void* d_ws, size_t ws_size,
                              hipStream_t stream) {
    const float* v1 = (const float*)d_in[0];
    const float* p1 = (const float*)d_in[1];
    const float* v2 = (const float*)d_in[2];
    const float* p2 = (const float*)d_in[3];
    float* out = (float*)d_out;
    const int N = in_sizes[1] / 10;  // prob_v1 is (N, 10)

    const int blocks = (N + RPB - 1) / RPB;
    fused_blend_kernel<<<blocks, 256, 0, stream>>>(v1, p1, v2, p2, out, N);
}

// Round 7
// 151.978 us; speedup vs baseline: 1.7212x; 1.0070x over previous
//
#include <hip/hip_runtime.h>
#include <math.h>

#define LAM 0.9f
#define EPS 1e-8f
#define RPB 256   // rows per block

typedef float f32x4 __attribute__((ext_vector_type(4)));
typedef float f32x2 __attribute__((ext_vector_type(2)));

// log-weight: 0.9*log(fir+eps) + 0.1*log(fir-sec+eps) over 10 probs
__device__ __forceinline__ float row_logw(const float* __restrict__ p) {
    float fir = -3.4e38f, sec = -3.4e38f;
    const f32x2* p2 = (const f32x2*)p;   // rows are 40B -> 8B-aligned
#pragma unroll
    for (int i = 0; i < 5; ++i) {
        f32x2 x = p2[i];
        if (x.x > fir) { sec = fir; fir = x.x; }
        else if (x.x > sec) { sec = x.x; }
        if (x.y > fir) { sec = fir; fir = x.y; }
        else if (x.y > sec) { sec = x.y; }
    }
    return LAM * __logf(fir + EPS) + (1.0f - LAM) * __logf(fir - sec + EPS);
}

__global__ __launch_bounds__(256) void fused_blend_kernel(
    const float* __restrict__ v1, const float* __restrict__ p1,
    const float* __restrict__ v2, const float* __restrict__ p2,
    float* __restrict__ out, int N)
{
    __shared__ float b1s[RPB];
    const int t   = threadIdx.x;
    const int t32 = t >> 5;
    const int rowBase = blockIdx.x * RPB;
    const int row = rowBase + t;
    const unsigned gBase = (unsigned)rowBase * 32u + (unsigned)t;   // flat float4 index

    const f32x4* __restrict__ v1q = (const f32x4*)v1;
    const f32x4* __restrict__ v2q = (const f32x4*)v2;
    f32x4* __restrict__ outq = (f32x4*)out;

    const bool full = (rowBase + RPB <= N);   // uniform per block

    if (full) {
        // Rotating window, distance 8: 8 pairs live (~64 data VGPRs), loads
        // for pair k+8 issued right after pair k is consumed. No fences, no
        // launch-bounds cap — the R6 failure withdrew both.
        f32x4 a[8], b[8];

        // Prime the window: issue pairs 0..7 before the beta phase so their
        // HBM latency hides under the prob loads + transcendentals.
#pragma unroll
        for (int j = 0; j < 8; ++j) {
            a[j] = v1q[gBase + (unsigned)j * 256u];
            b[j] = v2q[gBase + (unsigned)j * 256u];
        }

        // Phase 1: every thread computes beta1 for its own row.
        const float a1 = row_logw(p1 + (size_t)row * 10);
        const float a2 = row_logw(p2 + (size_t)row * 10);
        b1s[t] = 1.0f / (1.0f + __expf(a2 - a1));   // w1/(w1+w2) = sigmoid(a1-a2)
        __syncthreads();

        // Phase 2: blend+store pair k, then refill its slot with pair k+8.
#pragma unroll
        for (int k = 0; k < 32; ++k) {
            const int s = k & 7;
            const float be1 = b1s[k * 8 + t32];
            const f32x4 r = be1 * a[s] + (1.0f - be1) * b[s];
            __builtin_nontemporal_store(r, outq + gBase + (unsigned)k * 256u);
            if (k < 24) {
                a[s] = v1q[gBase + (unsigned)(k + 8) * 256u];
                b[s] = v2q[gBase + (unsigned)(k + 8) * 256u];
            }
        }
    } else {
        // Tail block (at most one): fully bounds-checked path.
        if (row < N) {
            const float a1 = row_logw(p1 + (size_t)row * 10);
            const float a2 = row_logw(p2 + (size_t)row * 10);
            b1s[t] = 1.0f / (1.0f + __expf(a2 - a1));
        }
        __syncthreads();
        const unsigned gEnd = (unsigned)N * 32u;
        for (int k = 0; k < 32; ++k) {
            const unsigned g = (unsigned)rowBase * 32u + (unsigned)k * 256u + (unsigned)t;
            if (g < gEnd) {
                const float be1 = b1s[(k * 256 + t) >> 5];
                const f32x4 va = v1q[g];
                const f32x4 vb = v2q[g];
                __builtin_nontemporal_store(be1 * va + (1.0f - be1) * vb, outq + g);
            }
        }
    }
}

extern "C" void kernel_launch(void* const* d_in, const int* in_sizes, int n_in,
                              void* d_out, int out_size, void* d_ws, size_t ws_size,
                              hipStream_t stream) {
    const float* v1 = (const float*)d_in[0];
    const float* p1 = (const float*)d_in[1];
    const float* v2 = (const float*)d_in[2];
    const float* p2 = (const float*)d_in[3];
    float* out = (float*)d_out;
    const int N = in_sizes[1] / 10;  // prob_v1 is (N, 10)

    const int blocks = (N + RPB - 1) / RPB;
    fused_blend_kernel<<<blocks, 256, 0, stream>>>(v1, p1, v2, p2, out, N);
}